// Round 1
// baseline (289.593 us; speedup 1.0000x reference)
//
#include <hip/hip_runtime.h>
#include <stdint.h>

#define D_EMB   64
#define N_ROWS  4096
#define DIM     512
#define KNEG    64
#define P_PAIRS 62
#define BPE     16           // blocks per embedding in pass1
#define EPSN    1e-8f
#define INV_T   10.0f

// Set to 0 if JAX runs with jax_threefry_partitionable=False (pre-0.4.36 default)
#define PARTITIONABLE 1

// ---------------- threefry-2x32-20 (matches JAX / Random123) ----------------
__device__ __forceinline__ uint32_t rotl32(uint32_t v, uint32_t r) {
  return (v << r) | (v >> (32u - r));
}

__device__ __forceinline__ void threefry(uint32_t k0, uint32_t k1,
                                         uint32_t c0, uint32_t c1,
                                         uint32_t& o0, uint32_t& o1) {
  uint32_t ks0 = k0, ks1 = k1, ks2 = k0 ^ k1 ^ 0x1BD11BDAu;
  uint32_t x0 = c0 + ks0, x1 = c1 + ks1;
#define RG(a,b,c,d) \
  x0 += x1; x1 = rotl32(x1,a); x1 ^= x0; \
  x0 += x1; x1 = rotl32(x1,b); x1 ^= x0; \
  x0 += x1; x1 = rotl32(x1,c); x1 ^= x0; \
  x0 += x1; x1 = rotl32(x1,d); x1 ^= x0;
  RG(13,15,26,6)   x0 += ks1; x1 += ks2 + 1u;
  RG(17,29,16,24)  x0 += ks2; x1 += ks0 + 2u;
  RG(13,15,26,6)   x0 += ks0; x1 += ks1 + 3u;
  RG(17,29,16,24)  x0 += ks1; x1 += ks2 + 4u;
  RG(13,15,26,6)   x0 += ks2; x1 += ks0 + 5u;
#undef RG
  o0 = x0; o1 = x1;
}

// ---------------- pass 1: row norms + per-block partial sums ----------------
// grid: D_EMB*BPE blocks, 256 threads. Each block: 256 rows of one embedding.
__global__ __launch_bounds__(256) void k_pass1(const float* __restrict__ I,
                                               float* __restrict__ partial,
                                               float* __restrict__ norms) {
  const int e = blockIdx.x / BPE, b = blockIdx.x % BPE;
  const int t = threadIdx.x, lane = t & 63, w = t >> 6;
  const float4* base = reinterpret_cast<const float4*>(I) + (size_t)e * N_ROWS * (DIM / 4);
  float acc[8] = {0.f,0.f,0.f,0.f,0.f,0.f,0.f,0.f};
  const int nbase = b * (N_ROWS / BPE);
  for (int i = 0; i < (N_ROWS / BPE) / 4; ++i) {
    const int n = nbase + i * 4 + w;
    const float4* row = base + (size_t)n * (DIM / 4);
    float4 A = row[lane];
    float4 B = row[lane + 64];
    acc[0] += A.x; acc[1] += A.y; acc[2] += A.z; acc[3] += A.w;
    acc[4] += B.x; acc[5] += B.y; acc[6] += B.z; acc[7] += B.w;
    float sq = A.x*A.x + A.y*A.y + A.z*A.z + A.w*A.w
             + B.x*B.x + B.y*B.y + B.z*B.z + B.w*B.w;
#pragma unroll
    for (int off = 32; off; off >>= 1) sq += __shfl_xor(sq, off);
    if (lane == 0) norms[e * N_ROWS + n] = sqrtf(sq);
  }
  __shared__ float lds[4 * DIM];
  const int p0 = 4 * lane;
#pragma unroll
  for (int q = 0; q < 4; ++q) {
    lds[w * DIM + p0 + q]       = acc[q];
    lds[w * DIM + 256 + p0 + q] = acc[4 + q];
  }
  __syncthreads();
  float s0 = lds[t] + lds[DIM + t] + lds[2*DIM + t] + lds[3*DIM + t];
  float s1 = lds[256 + t] + lds[DIM + 256 + t] + lds[2*DIM + 256 + t] + lds[3*DIM + 256 + t];
  float* out = partial + (size_t)(e * BPE + b) * DIM;
  out[t] = s0;
  out[256 + t] = s1;
}

// ---------------- pass 2: fold partials -> samples[0..63] (= sums) ----------
__global__ __launch_bounds__(256) void k_reduce(const float* __restrict__ partial,
                                                float* __restrict__ samples) {
  const int e = blockIdx.x, t = threadIdx.x;
  float s0 = 0.f, s1 = 0.f;
  for (int b = 0; b < BPE; ++b) {
    const float* pp = partial + (size_t)(e * BPE + b) * DIM;
    s0 += pp[t];
    s1 += pp[256 + t];
  }
  samples[e * DIM + t] = s0;
  samples[e * DIM + 256 + t] = s1;
}

// ---------------- top-64 row norms per embedding (iterative max-find) -------
__global__ __launch_bounds__(256) void k_topk(const float* __restrict__ norms,
                                              int* __restrict__ topidx) {
  const int e = blockIdx.x, t = threadIdx.x, lane = t & 63, w = t >> 6;
  __shared__ float vals[N_ROWS];
  __shared__ float rv[4];
  __shared__ int   ri[4];
  for (int i = t; i < N_ROWS; i += 256) vals[i] = norms[e * N_ROWS + i];
  __syncthreads();
  for (int k = 0; k < KNEG; ++k) {
    float bv = -1.f; int bi = -1;
    for (int i = t; i < N_ROWS; i += 256) {
      float v = vals[i];
      if (v > bv || (v == bv && (unsigned)i < (unsigned)bi)) { bv = v; bi = i; }
    }
#pragma unroll
    for (int off = 32; off; off >>= 1) {
      float ov = __shfl_xor(bv, off);
      int   oi = __shfl_xor(bi, off);
      if (ov > bv || (ov == bv && (unsigned)oi < (unsigned)bi)) { bv = ov; bi = oi; }
    }
    if (lane == 0) { rv[w] = bv; ri[w] = bi; }
    __syncthreads();
    if (t == 0) {
      float fv = rv[0]; int fi = ri[0];
      for (int q = 1; q < 4; ++q)
        if (rv[q] > fv || (rv[q] == fv && ri[q] < fi)) { fv = rv[q]; fi = ri[q]; }
      topidx[e * KNEG + k] = fi;
      vals[fi] = -1.f;
    }
    __syncthreads();
  }
}

// ---------------- subtract top-64 rows -> samples[64..127] (= sums_neg) -----
__global__ __launch_bounds__(256) void k_sumneg(const float* __restrict__ I,
                                                const int* __restrict__ topidx,
                                                float* __restrict__ samples) {
  const int e = blockIdx.x, t = threadIdx.x;
  const float* base = I + (size_t)e * N_ROWS * DIM;
  float a0 = 0.f, a1 = 0.f;
  for (int k = 0; k < KNEG; ++k) {
    const int r = topidx[e * KNEG + k];
    a0 += base[(size_t)r * DIM + t];
    a1 += base[(size_t)r * DIM + 256 + t];
  }
  samples[(D_EMB + e) * DIM + t]       = samples[e * DIM + t] - a0;
  samples[(D_EMB + e) * DIM + 256 + t] = samples[e * DIM + 256 + t] - a1;
}

// ---------------- sample norms + positive-pair scalar -----------------------
__global__ __launch_bounds__(256) void k_snorm(const float* __restrict__ samples,
                                               const float* __restrict__ g1,
                                               const float* __restrict__ g2,
                                               float* __restrict__ snorm,
                                               float* __restrict__ posp) {
  const int b = blockIdx.x, t = threadIdx.x, lane = t & 63, w = t >> 6;
  __shared__ float r0[4], r1[4], r2[4];
  if (b < 2 * D_EMB) {
    float a0 = samples[b * DIM + t], a1 = samples[b * DIM + 256 + t];
    float s = a0 * a0 + a1 * a1;
#pragma unroll
    for (int off = 32; off; off >>= 1) s += __shfl_xor(s, off);
    if (lane == 0) r0[w] = s;
    __syncthreads();
    if (t == 0) snorm[b] = fmaxf(sqrtf(r0[0] + r0[1] + r0[2] + r0[3]), EPSN);
  } else {
    float x0 = g1[t], x1 = g1[t + 256], y0 = g2[t], y1 = g2[t + 256];
    float d = x0 * y0 + x1 * y1, sa = x0 * x0 + x1 * x1, sb = y0 * y0 + y1 * y1;
#pragma unroll
    for (int off = 32; off; off >>= 1) {
      d  += __shfl_xor(d, off);
      sa += __shfl_xor(sa, off);
      sb += __shfl_xor(sb, off);
    }
    if (lane == 0) { r0[w] = d; r1[w] = sa; r2[w] = sb; }
    __syncthreads();
    if (t == 0) {
      float dt = r0[0] + r0[1] + r0[2] + r0[3];
      float s1 = r1[0] + r1[1] + r1[2] + r1[3];
      float s2 = r2[0] + r2[1] + r2[2] + r2[3];
      float c = dt / (fmaxf(sqrtf(s1), EPSN) * fmaxf(sqrtf(s2), EPSN));
      posp[0] = c * INV_T;
    }
  }
}

// ---------------- JAX-exact negative selection per pair ---------------------
// grid: P_PAIRS blocks, 128 threads
__global__ __launch_bounds__(128) void k_select(int* __restrict__ sel) {
  const int p = blockIdx.x;
  const int t = threadIdx.x;
  __shared__ uint32_t bits[126];
  __shared__ uint32_t sk[2];
  if (t == 0) {
#if PARTITIONABLE
    uint32_t kh, kl, a, b;
    threefry(0u, 42u, 0u, (uint32_t)p, kh, kl);   // keys[p] = split(key(42), 62)[p]
    threefry(kh, kl, 0u, 1u, a, b);               // subkey = split(keys[p])[1]
    sk[0] = a; sk[1] = b;
#else
    uint32_t kh, kl;
    { int idx = 2 * p; uint32_t a, b;
      if (idx < 62) { threefry(0u, 42u, (uint32_t)idx, (uint32_t)(62 + idx), a, b); kh = a; }
      else { int c = idx - 62; threefry(0u, 42u, (uint32_t)c, (uint32_t)(62 + c), a, b); kh = b; } }
    { int idx = 2 * p + 1; uint32_t a, b;
      if (idx < 62) { threefry(0u, 42u, (uint32_t)idx, (uint32_t)(62 + idx), a, b); kl = a; }
      else { int c = idx - 62; threefry(0u, 42u, (uint32_t)c, (uint32_t)(62 + c), a, b); kl = b; } }
    uint32_t a0, b0, a1, b1;
    threefry(kh, kl, 0u, 2u, a0, b0);
    threefry(kh, kl, 1u, 3u, a1, b1);
    sk[0] = b0; sk[1] = b1;
#endif
  }
  __syncthreads();
#if PARTITIONABLE
  if (t < 126) {
    uint32_t a, b;
    threefry(sk[0], sk[1], 0u, (uint32_t)t, a, b);
    bits[t] = a ^ b;                              // 32-bit partitionable path: bits1 ^ bits2
  }
#else
  if (t < 63) {
    uint32_t a, b;
    threefry(sk[0], sk[1], (uint32_t)t, (uint32_t)(63 + t), a, b);
    bits[t] = a; bits[63 + t] = b;
  }
#endif
  __syncthreads();
  if (t < 126) {
    const uint32_t myb = bits[t];
    int rank = 0;
    for (int j = 0; j < 126; ++j) {
      const uint32_t bj = bits[j];
      rank += ((bj < myb) || (bj == myb && j < t)) ? 1 : 0;
    }
    if (rank < KNEG) {                            // stable-argsort position < 64
      int v = t + (t >= p ? 1 : 0);               // cand mapping: skip i=p
      v += (v >= p + 2 ? 1 : 0);                  // then skip j=p+2
      sel[p * KNEG + rank] = v;
    }
  }
}

// ---------------- cosine sims + LSE + per-pair loss -------------------------
__global__ __launch_bounds__(256) void k_sims(const float* __restrict__ samples,
                                              const float* __restrict__ snorm,
                                              const int* __restrict__ sel,
                                              const float* __restrict__ posp,
                                              float* __restrict__ pairloss) {
  const int p = blockIdx.x;
  const int t = threadIdx.x, lane = t & 63, w = t >> 6;
  __shared__ float simi[KNEG], simj[KNEG];
  const float4* S = reinterpret_cast<const float4*>(samples);
  const float4 siA = S[p * 128 + lane],       siB = S[p * 128 + 64 + lane];
  const float4 sjA = S[(p + 2) * 128 + lane], sjB = S[(p + 2) * 128 + 64 + lane];
  const float ni = snorm[p], nj = snorm[p + 2];
  for (int k = w; k < KNEG; k += 4) {
    const int r = sel[p * KNEG + k];
    const float4 vA = S[r * 128 + lane], vB = S[r * 128 + 64 + lane];
    float di = siA.x*vA.x + siA.y*vA.y + siA.z*vA.z + siA.w*vA.w
             + siB.x*vB.x + siB.y*vB.y + siB.z*vB.z + siB.w*vB.w;
    float dj = sjA.x*vA.x + sjA.y*vA.y + sjA.z*vA.z + sjA.w*vA.w
             + sjB.x*vB.x + sjB.y*vB.y + sjB.z*vB.z + sjB.w*vB.w;
#pragma unroll
    for (int off = 32; off; off >>= 1) {
      di += __shfl_xor(di, off);
      dj += __shfl_xor(dj, off);
    }
    if (lane == 0) {
      const float nr = snorm[r];
      simi[k] = di / (ni * nr) * INV_T;
      simj[k] = dj / (nj * nr) * INV_T;
    }
  }
  __syncthreads();
  if (t == 0) {
    const float pos = posp[0];
    float mi = -1e30f, mj = -1e30f;
    for (int k = 0; k < KNEG; ++k) { mi = fmaxf(mi, simi[k]); mj = fmaxf(mj, simj[k]); }
    float si = 0.f, sj = 0.f;
    for (int k = 0; k < KNEG; ++k) { si += expf(simi[k] - mi); sj += expf(simj[k] - mj); }
    const float lsei = mi + logf(si), lsej = mj + logf(sj);
    const float li = fmaxf(pos, lsei) + log1pf(expf(-fabsf(pos - lsei))) - pos;
    const float lj = fmaxf(pos, lsej) + log1pf(expf(-fabsf(pos - lsej))) - pos;
    pairloss[p] = li + lj;
  }
}

// ---------------- final scalar sum ------------------------------------------
__global__ __launch_bounds__(64) void k_final(const float* __restrict__ pairloss,
                                              float* __restrict__ out) {
  const int t = threadIdx.x;
  float v = (t < P_PAIRS) ? pairloss[t] : 0.f;
#pragma unroll
  for (int off = 32; off; off >>= 1) v += __shfl_xor(v, off);
  if (t == 0) out[0] = v;
}

extern "C" void kernel_launch(void* const* d_in, const int* in_sizes, int n_in,
                              void* d_out, int out_size, void* d_ws, size_t ws_size,
                              hipStream_t stream) {
  const float* I  = (const float*)d_in[0];
  const float* g1 = (const float*)d_in[2];
  const float* g2 = (const float*)d_in[3];
  float* out = (float*)d_out;

  float* ws = (float*)d_ws;
  float* norms    = ws;                                   // 64*4096      = 262144
  float* partial  = ws + 262144;                          // 64*16*512    = 524288
  float* samples  = ws + 262144 + 524288;                 // 128*512      = 65536
  float* snorm    = samples + 65536;                      // 128
  float* posp     = snorm + 128;                          // 1 (+pad)
  float* pairloss = posp + 4;                             // 62
  int*   topidx   = (int*)(pairloss + 64);                // 64*64        = 4096
  int*   sel      = topidx + 4096;                        // 62*64        = 3968
  // total ~3.45 MB of d_ws

  k_pass1 <<<D_EMB * BPE, 256, 0, stream>>>(I, partial, norms);
  k_reduce<<<D_EMB,       256, 0, stream>>>(partial, samples);
  k_topk  <<<D_EMB,       256, 0, stream>>>(norms, topidx);
  k_sumneg<<<D_EMB,       256, 0, stream>>>(I, topidx, samples);
  k_snorm <<<2 * D_EMB + 1, 256, 0, stream>>>(samples, g1, g2, snorm, posp);
  k_select<<<P_PAIRS,     128, 0, stream>>>(sel);
  k_sims  <<<P_PAIRS,     256, 0, stream>>>(samples, snorm, sel, posp, pairloss);
  k_final <<<1,            64, 0, stream>>>(pairloss, out);
}

// Round 2
// 207.278 us; speedup vs baseline: 1.3971x; 1.3971x over previous
//
#include <hip/hip_runtime.h>
#include <stdint.h>

#define D_EMB   64
#define N_ROWS  4096
#define DIM     512
#define KNEG    64
#define P_PAIRS 62
#define BPE     32                      // blocks per embedding in pass1
#define ROWS_PER_BLK (N_ROWS / BPE)     // 128
#define EPSN    1e-8f
#define INV_T   10.0f

// ---------------- threefry-2x32-20 (matches JAX partitionable path) ---------
__device__ __forceinline__ uint32_t rotl32(uint32_t v, uint32_t r) {
  return (v << r) | (v >> (32u - r));
}

__device__ __forceinline__ void threefry(uint32_t k0, uint32_t k1,
                                         uint32_t c0, uint32_t c1,
                                         uint32_t& o0, uint32_t& o1) {
  uint32_t ks0 = k0, ks1 = k1, ks2 = k0 ^ k1 ^ 0x1BD11BDAu;
  uint32_t x0 = c0 + ks0, x1 = c1 + ks1;
#define RG(a,b,c,d) \
  x0 += x1; x1 = rotl32(x1,a); x1 ^= x0; \
  x0 += x1; x1 = rotl32(x1,b); x1 ^= x0; \
  x0 += x1; x1 = rotl32(x1,c); x1 ^= x0; \
  x0 += x1; x1 = rotl32(x1,d); x1 ^= x0;
  RG(13,15,26,6)   x0 += ks1; x1 += ks2 + 1u;
  RG(17,29,16,24)  x0 += ks2; x1 += ks0 + 2u;
  RG(13,15,26,6)   x0 += ks0; x1 += ks1 + 3u;
  RG(17,29,16,24)  x0 += ks1; x1 += ks2 + 4u;
  RG(13,15,26,6)   x0 += ks2; x1 += ks0 + 5u;
#undef RG
  o0 = x0; o1 = x1;
}

// ---------------- pass 1: row norms + per-block partial sums ----------------
// grid: D_EMB*BPE = 2048 blocks, 256 threads (8 waves/SIMD target).
__global__ __launch_bounds__(256, 8) void k_pass1(const float* __restrict__ I,
                                                  float* __restrict__ partial,
                                                  float* __restrict__ norms) {
  const int e = blockIdx.x / BPE, b = blockIdx.x % BPE;
  const int t = threadIdx.x, lane = t & 63, w = t >> 6;
  const float4* base = reinterpret_cast<const float4*>(I) + (size_t)e * N_ROWS * (DIM / 4);
  float acc[8] = {0.f,0.f,0.f,0.f,0.f,0.f,0.f,0.f};
  __shared__ float lds[4 * DIM];
  __shared__ float nlds[ROWS_PER_BLK];
  const int nbase = b * ROWS_PER_BLK;
  for (int i = 0; i < ROWS_PER_BLK / 4; ++i) {
    const int n = nbase + i * 4 + w;
    const float4* row = base + (size_t)n * (DIM / 4);
    float4 A = row[lane];
    float4 B = row[lane + 64];
    acc[0] += A.x; acc[1] += A.y; acc[2] += A.z; acc[3] += A.w;
    acc[4] += B.x; acc[5] += B.y; acc[6] += B.z; acc[7] += B.w;
    float sq = A.x*A.x + A.y*A.y + A.z*A.z + A.w*A.w
             + B.x*B.x + B.y*B.y + B.z*B.z + B.w*B.w;
#pragma unroll
    for (int off = 32; off; off >>= 1) sq += __shfl_xor(sq, off);
    if (lane == 0) nlds[i * 4 + w] = sqrtf(sq);
  }
  const int p0 = 4 * lane;
#pragma unroll
  for (int q = 0; q < 4; ++q) {
    lds[w * DIM + p0 + q]       = acc[q];
    lds[w * DIM + 256 + p0 + q] = acc[4 + q];
  }
  __syncthreads();
  float s0 = lds[t] + lds[DIM + t] + lds[2*DIM + t] + lds[3*DIM + t];
  float s1 = lds[256 + t] + lds[DIM + 256 + t] + lds[2*DIM + 256 + t] + lds[3*DIM + 256 + t];
  float* out = partial + (size_t)(e * BPE + b) * DIM;
  out[t] = s0;
  out[256 + t] = s1;
  if (t < ROWS_PER_BLK) norms[e * N_ROWS + nbase + t] = nlds[t];
}

// ---------------- kernel 2: per-embedding fold + top64 + sumneg + norms -----
// grid: D_EMB+1 blocks, 512 threads. Block D_EMB computes the positive pair.
__global__ __launch_bounds__(512) void k_embed(const float* __restrict__ I,
                                               const float* __restrict__ partial,
                                               const float* __restrict__ norms,
                                               const float* __restrict__ g1,
                                               const float* __restrict__ g2,
                                               float* __restrict__ samples,
                                               float* __restrict__ snorm,
                                               float* __restrict__ posp) {
  const int e = blockIdx.x;
  const int t = threadIdx.x, lane = t & 63, w = t >> 6;
  __shared__ float rA[8], rB[8], rC[8];

  if (e == D_EMB) {
    float x = g1[t], y = g2[t];
    float d = x * y, sa = x * x, sb = y * y;
#pragma unroll
    for (int off = 32; off; off >>= 1) {
      d  += __shfl_xor(d, off);
      sa += __shfl_xor(sa, off);
      sb += __shfl_xor(sb, off);
    }
    if (lane == 0) { rA[w] = d; rB[w] = sa; rC[w] = sb; }
    __syncthreads();
    if (t == 0) {
      float dt = 0.f, s1 = 0.f, s2 = 0.f;
      for (int q = 0; q < 8; ++q) { dt += rA[q]; s1 += rB[q]; s2 += rC[q]; }
      posp[0] = dt / (fmaxf(sqrtf(s1), EPSN) * fmaxf(sqrtf(s2), EPSN)) * INV_T;
    }
    return;
  }

  // ---- top-64 of norms[e], candidates held in registers ----
  float v[8];
#pragma unroll
  for (int q = 0; q < 8; ++q) v[q] = norms[e * N_ROWS + q * DIM + t];
  float lmax = v[0]; int lidx = t;
#pragma unroll
  for (int q = 1; q < 8; ++q)
    if (v[q] > lmax) { lmax = v[q]; lidx = q * DIM + t; }

  __shared__ float wbv[8];
  __shared__ int   wbi[8];
  __shared__ int   topidx[KNEG];
  for (int k = 0; k < KNEG; ++k) {
    float bv = lmax; int bi = lidx;
#pragma unroll
    for (int off = 32; off; off >>= 1) {
      float ov = __shfl_xor(bv, off);
      int   oi = __shfl_xor(bi, off);
      if (ov > bv || (ov == bv && oi < bi)) { bv = ov; bi = oi; }
    }
    if (lane == 0) { wbv[w] = bv; wbi[w] = bi; }
    __syncthreads();
    float fv = wbv[0]; int fi = wbi[0];
#pragma unroll
    for (int q = 1; q < 8; ++q)
      if (wbv[q] > fv || (wbv[q] == fv && wbi[q] < fi)) { fv = wbv[q]; fi = wbi[q]; }
    if (t == (fi & (DIM - 1))) {          // owner thread removes & rescans 8
      v[fi >> 9] = -1e30f;
      lmax = v[0]; lidx = t;
#pragma unroll
      for (int q = 1; q < 8; ++q)
        if (v[q] > lmax) { lmax = v[q]; lidx = q * DIM + t; }
    }
    if (t == 0) topidx[k] = fi;
    __syncthreads();
  }

  // ---- fold partials -> sums ----
  float s = 0.f;
  for (int b2 = 0; b2 < BPE; ++b2)
    s += partial[(size_t)(e * BPE + b2) * DIM + t];

  // ---- gather top-64 rows, subtract ----
  const float* base = I + (size_t)e * N_ROWS * DIM;
  float a = 0.f;
#pragma unroll 4
  for (int k = 0; k < KNEG; ++k)
    a += base[(size_t)topidx[k] * DIM + t];
  float sn = s - a;

  // ---- norms of both sample rows ----
  float q1 = s * s, q2 = sn * sn;
#pragma unroll
  for (int off = 32; off; off >>= 1) {
    q1 += __shfl_xor(q1, off);
    q2 += __shfl_xor(q2, off);
  }
  if (lane == 0) { rA[w] = q1; rB[w] = q2; }
  __syncthreads();
  if (t == 0) {
    float n1 = 0.f, n2 = 0.f;
    for (int q = 0; q < 8; ++q) { n1 += rA[q]; n2 += rB[q]; }
    snorm[e]         = fmaxf(sqrtf(n1), EPSN);
    snorm[D_EMB + e] = fmaxf(sqrtf(n2), EPSN);
  }
  samples[(size_t)e * DIM + t]           = s;
  samples[(size_t)(D_EMB + e) * DIM + t] = sn;
}

// ---------------- kernel 3: select + cosine sims + LSE + pair loss ----------
// grid: P_PAIRS blocks, 256 threads
__global__ __launch_bounds__(256) void k_pair(const float* __restrict__ samples,
                                              const float* __restrict__ snorm,
                                              const float* __restrict__ posp,
                                              float* __restrict__ pairloss) {
  const int p = blockIdx.x;
  const int t = threadIdx.x, lane = t & 63, w = t >> 6;
  __shared__ uint32_t bits[126];
  __shared__ uint32_t sk[2];
  __shared__ int      sel[KNEG];
  __shared__ float    simi[KNEG], simj[KNEG];

  if (t == 0) {
    uint32_t kh, kl, a, b;
    threefry(0u, 42u, 0u, (uint32_t)p, kh, kl);   // keys[p] = split(key(42), 62)[p]
    threefry(kh, kl, 0u, 1u, a, b);               // subkey = split(keys[p])[1]
    sk[0] = a; sk[1] = b;
  }
  __syncthreads();
  if (t < 126) {
    uint32_t a, b;
    threefry(sk[0], sk[1], 0u, (uint32_t)t, a, b);
    bits[t] = a ^ b;                              // partitionable 32-bit path
  }
  __syncthreads();
  if (t < 126) {
    const uint32_t myb = bits[t];
    int rank = 0;
    for (int j = 0; j < 126; ++j) {
      const uint32_t bj = bits[j];
      rank += ((bj < myb) || (bj == myb && j < t)) ? 1 : 0;
    }
    if (rank < KNEG) {
      int vv = t + (t >= p ? 1 : 0);              // cand mapping: skip i=p
      vv += (vv >= p + 2 ? 1 : 0);                // then skip j=p+2
      sel[rank] = vv;
    }
  }
  __syncthreads();

  const float4* S = reinterpret_cast<const float4*>(samples);
  const float4 siA = S[p * 128 + lane],       siB = S[p * 128 + 64 + lane];
  const float4 sjA = S[(p + 2) * 128 + lane], sjB = S[(p + 2) * 128 + 64 + lane];
  const float ni = snorm[p], nj = snorm[p + 2];
  for (int k = w; k < KNEG; k += 4) {
    const int r = sel[k];
    const float4 vA = S[r * 128 + lane], vB = S[r * 128 + 64 + lane];
    float di = siA.x*vA.x + siA.y*vA.y + siA.z*vA.z + siA.w*vA.w
             + siB.x*vB.x + siB.y*vB.y + siB.z*vB.z + siB.w*vB.w;
    float dj = sjA.x*vA.x + sjA.y*vA.y + sjA.z*vA.z + sjA.w*vA.w
             + sjB.x*vB.x + sjB.y*vB.y + sjB.z*vB.z + sjB.w*vB.w;
#pragma unroll
    for (int off = 32; off; off >>= 1) {
      di += __shfl_xor(di, off);
      dj += __shfl_xor(dj, off);
    }
    if (lane == 0) {
      const float nr = snorm[r];
      simi[k] = di / (ni * nr) * INV_T;
      simj[k] = dj / (nj * nr) * INV_T;
    }
  }
  __syncthreads();
  if (t < KNEG) {                                  // wave 0 only
    const float xi = simi[t], xj = simj[t];
    float mi = xi, mj = xj;
#pragma unroll
    for (int off = 32; off; off >>= 1) {
      mi = fmaxf(mi, __shfl_xor(mi, off));
      mj = fmaxf(mj, __shfl_xor(mj, off));
    }
    float ei = expf(xi - mi), ej = expf(xj - mj);
#pragma unroll
    for (int off = 32; off; off >>= 1) {
      ei += __shfl_xor(ei, off);
      ej += __shfl_xor(ej, off);
    }
    if (t == 0) {
      const float pos = posp[0];
      const float lsei = mi + logf(ei), lsej = mj + logf(ej);
      const float li = fmaxf(pos, lsei) + log1pf(expf(-fabsf(pos - lsei))) - pos;
      const float lj = fmaxf(pos, lsej) + log1pf(expf(-fabsf(pos - lsej))) - pos;
      pairloss[p] = li + lj;
    }
  }
}

// ---------------- final scalar sum ------------------------------------------
__global__ __launch_bounds__(64) void k_final(const float* __restrict__ pairloss,
                                              float* __restrict__ out) {
  const int t = threadIdx.x;
  float v = (t < P_PAIRS) ? pairloss[t] : 0.f;
#pragma unroll
  for (int off = 32; off; off >>= 1) v += __shfl_xor(v, off);
  if (t == 0) out[0] = v;
}

extern "C" void kernel_launch(void* const* d_in, const int* in_sizes, int n_in,
                              void* d_out, int out_size, void* d_ws, size_t ws_size,
                              hipStream_t stream) {
  const float* I  = (const float*)d_in[0];
  const float* g1 = (const float*)d_in[2];
  const float* g2 = (const float*)d_in[3];
  float* out = (float*)d_out;

  float* ws = (float*)d_ws;
  float* norms    = ws;                                   // 64*4096        = 262144
  float* partial  = ws + 262144;                          // 64*32*512      = 1048576
  float* samples  = partial + 1048576;                    // 128*512        = 65536
  float* snorm    = samples + 65536;                      // 128
  float* posp     = snorm + 128;                          // 1 (+pad)
  float* pairloss = posp + 4;                             // 62 (+pad)

  k_pass1<<<D_EMB * BPE, 256, 0, stream>>>(I, partial, norms);
  k_embed<<<D_EMB + 1,   512, 0, stream>>>(I, partial, norms, g1, g2,
                                           samples, snorm, posp);
  k_pair <<<P_PAIRS,     256, 0, stream>>>(samples, snorm, posp, pairloss);
  k_final<<<1,            64, 0, stream>>>(pairloss, out);
}